// Round 6
// baseline (1337.057 us; speedup 1.0000x reference)
//
#include <hip/hip_runtime.h>
#include <math.h>

#define HDIM 70
#define HPAD 72
#define GATES 280
#define NG 288        // gates padded to 18*16
#define TLEN 512
#define BATCH 128
#define CDIM 1104
#define KW 1152       // K padded to 18*64
#define ROWS 65536    // BATCH*TLEN

// ws layout (float offsets)
#define OFF_WRN   0          // 1104*70 fp32 -> 77280 (round 77312)
#define OFF_BIAS  77312      // 280 fp32 (round 320)
#define OFF_WCT   77632      // 288*1152 bf16 = 165888 floats
#define OFF_XG    243520     // 65536*280 bf16 = 9175040 floats (xg2 layout, same size)
#define OFF_HOUT  9418560    // 65536*72 fp32 = 4718592
#define OFF_EN    14137152   // 65536 fp32
#define OFF_WHH   0          // 320*96 bf16 = 15360 floats, aliases WRN (wrn dead after k_prep)

typedef short short8 __attribute__((ext_vector_type(8)));
typedef float f32x4 __attribute__((ext_vector_type(4)));

__device__ __forceinline__ unsigned short f2bf(float f) {
    unsigned int u = __float_as_uint(f);
    u = (u + 0x7fffu + ((u >> 16) & 1u)) >> 16;
    return (unsigned short)u;
}
__device__ __forceinline__ float bf2f(unsigned short s) {
    return __uint_as_float(((unsigned int)s) << 16);
}

// ---------------- K1: row renorm of embed_w ----------------
__global__ __launch_bounds__(64) void k_renorm(const float* __restrict__ w,
                                               float* __restrict__ wrn) {
    const int row = blockIdx.x;
    const int lane = threadIdx.x;
    const float* wr = w + row * HDIM;
    float v0 = wr[lane];
    float v1 = (lane < 6) ? wr[64 + lane] : 0.0f;
    float ss = v0 * v0 + v1 * v1;
    #pragma unroll
    for (int off = 32; off > 0; off >>= 1) ss += __shfl_down(ss, off);
    float tot = __shfl(ss, 0);
    float n = sqrtf(tot);
    float scale = (n > 1.0f) ? 1.0f / (n + 1e-7f) : 1.0f;
    wrn[row * HDIM + lane] = v0 * scale;
    if (lane < 6) wrn[row * HDIM + 64 + lane] = v1 * scale;
}

// ---------------- K2: WcT[n][k] = sum_h w_ih[n][h]*wrn[k][h], bf16, padded ----------------
__global__ __launch_bounds__(256) void k_prep(const float* __restrict__ wrn,
                                              const float* __restrict__ w_ih,
                                              const float* __restrict__ b_ih,
                                              const float* __restrict__ b_hh,
                                              unsigned short* __restrict__ wcT,
                                              float* __restrict__ bias) {
    const int n = blockIdx.x;      // 0..287
    const int tid = threadIdx.x;
    float wr[HDIM];
    if (n < GATES) {
        #pragma unroll
        for (int h = 0; h < HDIM; ++h) wr[h] = w_ih[n * HDIM + h];
        if (tid == 0) bias[n] = b_ih[n] + b_hh[n];
    } else {
        #pragma unroll
        for (int h = 0; h < HDIM; ++h) wr[h] = 0.0f;
    }
    for (int c = tid; c < KW; c += 256) {
        float a = 0.0f;
        if (n < GATES && c < CDIM) {
            const float* wc = wrn + c * HDIM;
            #pragma unroll
            for (int h = 0; h < HDIM; ++h) a += wr[h] * wc[h];
        }
        wcT[(size_t)n * KW + c] = f2bf(a);
    }
}

// ---------------- K2b: Whh padded bf16 [320][96]: row g*80+j, col k ----------------
__global__ __launch_bounds__(96) void k_prep_whh(const float* __restrict__ w_hh,
                                                 unsigned short* __restrict__ whh) {
    const int rrow = blockIdx.x;   // 0..319
    const int k = threadIdx.x;     // 0..95
    const int g = rrow / 80;
    const int j = rrow % 80;
    float v = (j < HDIM && k < HDIM) ? w_hh[(size_t)(g * HDIM + j) * HDIM + k] : 0.0f;
    whh[(size_t)rrow * 96 + k] = f2bf(v);
}

// ---------------- K3: xg2 = x @ Wc + bias (bf16 MFMA) ----------------
// output layout: xg2[((b8*512 + t)*16 + bi)*280 + gate], b8 = b>>4, bi = b&15
__global__ __launch_bounds__(256, 2) void k_xg_gemm(const float* __restrict__ x,
                                                    const unsigned short* __restrict__ wcT,
                                                    const float* __restrict__ bias,
                                                    unsigned short* __restrict__ xg) {
    __shared__ __align__(16) unsigned short A_lds[128 * 72];  // [row][k] stride 72
    __shared__ __align__(16) unsigned short B_lds[NG * 72];   // [n][k]   stride 72
    const int tid = threadIdx.x;
    const int lane = tid & 63;
    const int w = tid >> 6;
    const int mh = (w >> 1) * 64;     // wave M-half: 0 or 64
    const int nh = (w & 1) * 144;     // wave N-half: 0 or 144 (9 n-tiles)
    const int l15 = lane & 15;
    const int q = lane >> 4;
    const size_t rbase = (size_t)blockIdx.x * 128;

    f32x4 acc[4][9];
    #pragma unroll
    for (int mt = 0; mt < 4; ++mt)
        #pragma unroll
        for (int nt = 0; nt < 9; ++nt) acc[mt][nt] = (f32x4){0.f, 0.f, 0.f, 0.f};

    const int r_st = tid >> 1;
    const int kh_st = (tid & 1) * 32;

    for (int kc = 0; kc < 18; ++kc) {
        const int k0 = kc * 64;
        // stage A: 128 rows x 64 k fp32 -> bf16
        {
            const float* xr = x + (rbase + r_st) * (size_t)CDIM + k0 + kh_st;
            unsigned short* dst = &A_lds[r_st * 72 + kh_st];
            #pragma unroll
            for (int qq = 0; qq < 8; ++qq) {
                const int kk = k0 + kh_st + qq * 4;
                float4 v = make_float4(0.f, 0.f, 0.f, 0.f);
                if (kk < CDIM) v = *(const float4*)(xr + qq * 4);
                unsigned int lo = (unsigned int)f2bf(v.x) | ((unsigned int)f2bf(v.y) << 16);
                unsigned int hi = (unsigned int)f2bf(v.z) | ((unsigned int)f2bf(v.w) << 16);
                uint2 pv; pv.x = lo; pv.y = hi;
                *(uint2*)&dst[qq * 4] = pv;
            }
        }
        // stage B: 288 n x 64 k bf16 (already padded with zeros)
        {
            #pragma unroll
            for (int p = 0; p < 9; ++p) {
                const int cid = tid + p * 256;
                const int n = cid >> 3;
                const int ko = (cid & 7) * 8;
                uint4 v = *(const uint4*)(wcT + (size_t)n * KW + k0 + ko);
                *(uint4*)&B_lds[n * 72 + ko] = v;
            }
        }
        __syncthreads();
        #pragma unroll
        for (int ks = 0; ks < 2; ++ks) {
            short8 a[4];
            short8 bfr[9];
            #pragma unroll
            for (int mt = 0; mt < 4; ++mt)
                a[mt] = *(const short8*)&A_lds[(mh + mt * 16 + l15) * 72 + ks * 32 + q * 8];
            #pragma unroll
            for (int nt = 0; nt < 9; ++nt)
                bfr[nt] = *(const short8*)&B_lds[(nh + nt * 16 + l15) * 72 + ks * 32 + q * 8];
            #pragma unroll
            for (int mt = 0; mt < 4; ++mt)
                #pragma unroll
                for (int nt = 0; nt < 9; ++nt)
                    acc[mt][nt] = __builtin_amdgcn_mfma_f32_16x16x32_bf16(a[mt], bfr[nt], acc[mt][nt], 0, 0, 0);
        }
        __syncthreads();
    }
    // epilogue: + bias, store bf16 in xg2 layout
    #pragma unroll
    for (int nt = 0; nt < 9; ++nt) {
        const int n_g = nh + nt * 16 + l15;
        if (n_g >= GATES) continue;
        const float bv = bias[n_g];
        #pragma unroll
        for (int mt = 0; mt < 4; ++mt) {
            #pragma unroll
            for (int r = 0; r < 4; ++r) {
                const size_t row = rbase + mh + mt * 16 + q * 4 + r;
                const int bb = (int)(row >> 9);
                const int tt = (int)(row & 511);
                xg[((size_t)((bb >> 4) * 512 + tt) * 16 + (bb & 15)) * GATES + n_g] =
                    f2bf(acc[mt][nt][r] + bv);
            }
        }
    }
}

// ---------------- K4: LSTM scan — 16 batches/block, MFMA recurrent GEMM ----------------
// grid 8 blocks x 384 thr (waves 0-4 compute, wave 5 IO).
// Recurrence: gates[320pad x 16] = WhhPad[320x96] . H[96x16] via 12 mfma_16x16x32_bf16/wave.
// Row map g*80+j => lane (col=batch=l15, rows q*4+r) holds ALL 4 gates of (j,batch):
// c/h update lane-local, zero exchange. H double-buffered in LDS [16][104] bf16.
// IO wave stages xg tiles into a 4-slot ring 2-4 steps ahead (reg ping-pong).
__device__ __forceinline__ float sigmoid_fast(float v) {
    return 1.0f / (1.0f + __expf(-v));
}

#define RSLOT 4496   // shorts per ring slot (16*280 + 16 pad)

__global__ __launch_bounds__(384, 1) void k_lstm(const unsigned short* __restrict__ xg,
                                                 const unsigned short* __restrict__ whh,
                                                 float* __restrict__ hout) {
    __shared__ __align__(16) unsigned short Hb[2][16 * 104];   // [buf][batch][k pad 104]
    __shared__ __align__(16) unsigned short ring[4][RSLOT];
    const int tid = threadIdx.x;
    const int b8 = blockIdx.x;          // batch group (16 batches)
    const int wv = tid >> 6;            // 0..5
    const int l = tid & 63;
    const int l15 = l & 15;             // batch within group / fragment col
    const int q = l >> 4;
    const unsigned short* xgb = xg + (size_t)b8 * TLEN * 16 * GATES;

    // zero H buffers (covers padded k 70..103)
    for (int i = tid; i < 16 * 104; i += 384) ((unsigned int*)Hb)[i] = 0u;

    short8 afr[4][3];
    uint4 r0[9], r1[9];
    if (wv < 5) {
        // A-fragments: Whh rows (5g+wv)*16 + l15, k = ks*32 + q*8 .. +8
        #pragma unroll
        for (int g = 0; g < 4; ++g)
            #pragma unroll
            for (int ks = 0; ks < 3; ++ks)
                afr[g][ks] = *(const short8*)&whh[(size_t)((5 * g + wv) * 16 + l15) * 96 + ks * 32 + q * 8];
    } else {
        // stage ring slots 0,1; preload regs for steps 2,3
        #pragma unroll
        for (int s = 0; s < 2; ++s)
            for (int c = l; c < 560; c += 64)
                *(uint4*)&ring[s][c * 8] = *(const uint4*)(xgb + (size_t)s * 16 * GATES + c * 8);
        #pragma unroll
        for (int i = 0; i < 9; ++i) {
            const int c = l + i * 64;
            if (c < 560) {
                r0[i] = *(const uint4*)(xgb + (size_t)2 * 16 * GATES + c * 8);
                r1[i] = *(const uint4*)(xgb + (size_t)3 * 16 * GATES + c * 8);
            }
        }
    }
    const int jb = wv * 16 + q * 4;     // base j of this lane's 4 rows (compute waves)
    float creg[4] = {0.f, 0.f, 0.f, 0.f};
    __syncthreads();

    #pragma unroll 4
    for (int t = 0; t < TLEN; ++t) {
        if (wv < 5) {
            // xg for this lane's 16 (g,r) pre-activations
            const unsigned short* rg = &ring[t & 3][l15 * GATES];
            float u[4][4];
            #pragma unroll
            for (int g = 0; g < 4; ++g) {
                const int base = g * 70 + jb;
                const unsigned int w0 = *(const unsigned int*)&rg[base];
                const unsigned int w1 = *(const unsigned int*)&rg[base + 2];
                u[g][0] = bf2f((unsigned short)(w0 & 0xffffu));
                u[g][1] = bf2f((unsigned short)(w0 >> 16));
                u[g][2] = bf2f((unsigned short)(w1 & 0xffffu));
                u[g][3] = bf2f((unsigned short)(w1 >> 16));
            }
            // B-fragments from H(t-1), 12 MFMAs
            const unsigned short* hb = &Hb[t & 1][l15 * 104];
            f32x4 acc[4];
            #pragma unroll
            for (int g = 0; g < 4; ++g) acc[g] = (f32x4){0.f, 0.f, 0.f, 0.f};
            #pragma unroll
            for (int ks = 0; ks < 3; ++ks) {
                const short8 bfr = *(const short8*)&hb[ks * 32 + q * 8];
                #pragma unroll
                for (int g = 0; g < 4; ++g)
                    acc[g] = __builtin_amdgcn_mfma_f32_16x16x32_bf16(afr[g][ks], bfr, acc[g], 0, 0, 0);
            }
            // gates -> c,h (all lane-local); mask invalid j rows (NaN containment)
            float h[4];
            #pragma unroll
            for (int r = 0; r < 4; ++r) {
                const float iv = sigmoid_fast(acc[0][r] + u[0][r]);
                const float fv = sigmoid_fast(acc[1][r] + u[1][r]);
                const float gv = fmaf(2.f, sigmoid_fast(2.f * (acc[2][r] + u[2][r])), -1.f);
                const float ov = sigmoid_fast(acc[3][r] + u[3][r]);
                creg[r] = fmaf(fv, creg[r], iv * gv);
                const float hv = ov * fmaf(2.f, sigmoid_fast(2.f * creg[r]), -1.f);
                h[r] = (jb + r < HDIM) ? hv : 0.f;
            }
            // h -> Hb[(t+1)&1] as bf16 (4 vals contiguous at [l15][jb])
            uint2 pp;
            pp.x = (unsigned int)f2bf(h[0]) | ((unsigned int)f2bf(h[1]) << 16);
            pp.y = (unsigned int)f2bf(h[2]) | ((unsigned int)f2bf(h[3]) << 16);
            *(uint2*)&Hb[(t + 1) & 1][l15 * 104 + jb] = pp;
            // hout store (fp32)
            float* hop = hout + ((size_t)(b8 * 16 + l15) * TLEN + t) * HPAD + jb;
            if (jb + 3 < HDIM) {
                *(float4*)hop = make_float4(h[0], h[1], h[2], h[3]);
            } else if (jb < HDIM) {
                hop[0] = h[0]; hop[1] = h[1];   // jb == 68
            }
        } else {
            // IO wave: write step t+2 from regs, issue load for t+4
            uint4* dst = (uint4*)&ring[(t + 2) & 3][0];
            if ((t & 1) == 0) {
                if (t + 2 < TLEN) {
                    #pragma unroll
                    for (int i = 0; i < 9; ++i) { const int c = l + i * 64; if (c < 560) dst[c] = r0[i]; }
                }
                if (t + 4 < TLEN) {
                    const unsigned short* src = xgb + (size_t)(t + 4) * 16 * GATES;
                    #pragma unroll
                    for (int i = 0; i < 9; ++i) { const int c = l + i * 64; if (c < 560) r0[i] = *(const uint4*)(src + c * 8); }
                }
            } else {
                if (t + 2 < TLEN) {
                    #pragma unroll
                    for (int i = 0; i < 9; ++i) { const int c = l + i * 64; if (c < 560) dst[c] = r1[i]; }
                }
                if (t + 4 < TLEN) {
                    const unsigned short* src = xgb + (size_t)(t + 4) * 16 * GATES;
                    #pragma unroll
                    for (int i = 0; i < 9; ++i) { const int c = l + i * 64; if (c < 560) r1[i] = *(const uint4*)(src + c * 8); }
                }
            }
        }
        // LDS handoff only: no vmcnt drain on compute critical path
        asm volatile("s_waitcnt lgkmcnt(0)" ::: "memory");
        __builtin_amdgcn_s_barrier();
        __builtin_amdgcn_sched_barrier(0);
    }
}

// ---------------- K5a: attention energy ----------------
__global__ __launch_bounds__(256) void k_energy(const float* __restrict__ hout,
                                                const float* __restrict__ w1,
                                                const float* __restrict__ b1,
                                                const float* __restrict__ w2,
                                                const float* __restrict__ b2,
                                                float* __restrict__ energy) {
    const int lane = threadIdx.x & 63;
    const int wid = blockIdx.x * 4 + (threadIdx.x >> 6);
    float w1r[HPAD];
    #pragma unroll
    for (int c = 0; c < HDIM; ++c) w1r[c] = w1[lane * HDIM + c];
    w1r[70] = w1r[71] = 0.0f;
    const float b1v = b1[lane];
    const float w2v = w2[lane];
    const float b2v = b2[0];
    for (int row = wid; row < ROWS; row += 4096) {
        const float4* rp = (const float4*)(hout + (size_t)row * HPAD);
        float a0 = 0.f, a1 = 0.f, a2 = 0.f, a3 = 0.f;
        #pragma unroll
        for (int jj = 0; jj < 18; ++jj) {
            float4 v = rp[jj];
            a0 += v.x * w1r[4 * jj];
            a1 += v.y * w1r[4 * jj + 1];
            a2 += v.z * w1r[4 * jj + 2];
            a3 += v.w * w1r[4 * jj + 3];
        }
        float hid = fmaxf((a0 + a1) + (a2 + a3) + b1v, 0.0f) * w2v;
        #pragma unroll
        for (int off = 32; off > 0; off >>= 1) hid += __shfl_down(hid, off);
        if (lane == 0) energy[row] = hid + b2v;
    }
}

// ---------------- K5b: softmax-pool + FC + softmax ----------------
__global__ __launch_bounds__(128) void k_pool(const float* __restrict__ hout,
                                              const float* __restrict__ energy,
                                              const float* __restrict__ fc_w,
                                              const float* __restrict__ fc_b,
                                              float* __restrict__ outp) {
    __shared__ float red[128];
    __shared__ float wexp[TLEN];
    __shared__ float pooledL[HDIM];
    const int tid = threadIdx.x;
    const int b = blockIdx.x;
    float v[4];
    #pragma unroll
    for (int k = 0; k < 4; ++k) v[k] = energy[b * TLEN + tid + 128 * k];
    float m = fmaxf(fmaxf(v[0], v[1]), fmaxf(v[2], v[3]));
    red[tid] = m; __syncthreads();
    for (int s = 64; s > 0; s >>= 1) {
        if (tid < s) red[tid] = fmaxf(red[tid], red[tid + s]);
        __syncthreads();
    }
    const float M = red[0]; __syncthreads();
    float s4 = 0.f;
    #pragma unroll
    for (int k = 0; k < 4; ++k) {
        float ex = __expf(v[k] - M);
        wexp[tid + 128 * k] = ex;
        s4 += ex;
    }
    red[tid] = s4; __syncthreads();
    for (int s = 64; s > 0; s >>= 1) {
        if (tid < s) red[tid] += red[tid + s];
        __syncthreads();
    }
    const float rinv = 1.0f / red[0];
    if (tid < HDIM) {
        float a0 = 0.f, a1 = 0.f, a2 = 0.f, a3 = 0.f;
        const float* hp = hout + (size_t)b * TLEN * HPAD + tid;
        for (int s = 0; s < TLEN; s += 4) {
            a0 += wexp[s]     * hp[(size_t)(s)     * HPAD];
            a1 += wexp[s + 1] * hp[(size_t)(s + 1) * HPAD];
            a2 += wexp[s + 2] * hp[(size_t)(s + 2) * HPAD];
            a3 += wexp[s + 3] * hp[(size_t)(s + 3) * HPAD];
        }
        pooledL[tid] = ((a0 + a1) + (a2 + a3)) * rinv;
    }
    __syncthreads();
    if (tid == 0) {
        float l[3];
        #pragma unroll
        for (int i = 0; i < 3; ++i) {
            float a = fc_b[i];
            for (int h = 0; h < HDIM; ++h) a += fc_w[i * HDIM + h] * pooledL[h];
            l[i] = a;
        }
        float m3 = fmaxf(l[0], fmaxf(l[1], l[2]));
        float e0 = __expf(l[0] - m3), e1 = __expf(l[1] - m3), e2 = __expf(l[2] - m3);
        float rs = 1.0f / (e0 + e1 + e2);
        outp[b * 3 + 0] = e0 * rs;
        outp[b * 3 + 1] = e1 * rs;
        outp[b * 3 + 2] = e2 * rs;
    }
}

extern "C" void kernel_launch(void* const* d_in, const int* in_sizes, int n_in,
                              void* d_out, int out_size, void* d_ws, size_t ws_size,
                              hipStream_t stream) {
    const float* x       = (const float*)d_in[0];
    const float* embed_w = (const float*)d_in[1];
    const float* w_ih    = (const float*)d_in[2];
    const float* w_hh    = (const float*)d_in[3];
    const float* b_ih    = (const float*)d_in[4];
    const float* b_hh    = (const float*)d_in[5];
    const float* aw1     = (const float*)d_in[6];
    const float* ab1     = (const float*)d_in[7];
    const float* aw2     = (const float*)d_in[8];
    const float* ab2     = (const float*)d_in[9];
    const float* fc_w    = (const float*)d_in[10];
    const float* fc_b    = (const float*)d_in[11];
    float* outp = (float*)d_out;
    float* ws = (float*)d_ws;

    float* wrn  = ws + OFF_WRN;
    float* bias = ws + OFF_BIAS;
    unsigned short* wcT  = (unsigned short*)(ws + OFF_WCT);
    unsigned short* xgp  = (unsigned short*)(ws + OFF_XG);
    unsigned short* whhp = (unsigned short*)(ws + OFF_WHH);
    float* ho = ws + OFF_HOUT;
    float* en = ws + OFF_EN;

    k_renorm<<<CDIM, 64, 0, stream>>>(embed_w, wrn);
    k_prep<<<NG, 256, 0, stream>>>(wrn, w_ih, b_ih, b_hh, wcT, bias);
    k_prep_whh<<<320, 96, 0, stream>>>(w_hh, whhp);   // after k_prep: aliases dead wrn
    k_xg_gemm<<<512, 256, 0, stream>>>(x, wcT, bias, xgp);
    k_lstm<<<8, 384, 0, stream>>>(xgp, whhp, ho);
    k_energy<<<1024, 256, 0, stream>>>(ho, aw1, ab1, aw2, ab2, en);
    k_pool<<<BATCH, 128, 0, stream>>>(ho, en, fc_w, fc_b, outp);
}